// Round 5
// baseline (119.628 us; speedup 1.0000x reference)
//
#include <hip/hip_runtime.h>
#include <hip/hip_bf16.h>

// Fused spatial self-attention, B=4 C=64 H=W=64 (N=4096), fp32 in/out.
// Round 5: KVBLK=32 + XOR-swizzled LDS (no pad), splits=8 (32 waves/CU),
// XCD-chunked block swizzle, exp2-domain softmax (log2e folded into Q).
// kernel 1 = exact fp32 QKV projection -> q (x log2e), k (N,C) fp16, v (C,N) fp16.
// kernel 2 = flash attention, split-j, fp16 16x16x32 MFMA.
// kernel 3 = merge normalized partials.

using f16    = _Float16;
using f16x8  = __attribute__((ext_vector_type(8))) f16;
using f32x4  = __attribute__((ext_vector_type(4))) float;

static constexpr int NB = 4;     // batch
static constexpr int NC = 64;    // channels
static constexpr int NT = 4096;  // tokens (H*W)
static constexpr int KVB = 32;   // keys per j-tile
static constexpr float LOG2E = 1.44269504088896f;

__device__ __forceinline__ float fexp2(float x) { return __builtin_amdgcn_exp2f(x); }

// ---------------- kernel 1: QKV projection (exact fp32) ----------------
// grid = 3 * B * (N/64); blockIdx>>8 selects projection (q/k/v).
__global__ __launch_bounds__(256) void qkv_proj(
    const float* __restrict__ x,
    const float* __restrict__ Wq, const float* __restrict__ bq,
    const float* __restrict__ Wk, const float* __restrict__ bk,
    const float* __restrict__ Wv, const float* __restrict__ bv,
    f16* __restrict__ qh, f16* __restrict__ kh, f16* __restrict__ vv)
{
    __shared__ float xs[64][68];   // [n][c], transposed x tile (pad for b128)
    __shared__ float ws[64][64];   // projection weight [o][c]

    const int t  = threadIdx.x;
    const int p  = blockIdx.x >> 8;          // 0=q 1=k 2=v
    const int b  = (blockIdx.x >> 6) & 3;
    const int n0 = (blockIdx.x & 63) << 6;

    const float* Wp = (p == 0) ? Wq : (p == 1) ? Wk : Wv;
    const float* bp = (p == 0) ? bq : (p == 1) ? bk : bv;

    #pragma unroll
    for (int i = 0; i < 4; ++i) {
        const int idx = i * 256 + t;
        const int c = idx >> 4, n4 = (idx & 15) << 2;
        const float4 xv = *reinterpret_cast<const float4*>(
            x + ((size_t)(b * NC + c)) * NT + n0 + n4);
        xs[n4 + 0][c] = xv.x; xs[n4 + 1][c] = xv.y;
        xs[n4 + 2][c] = xv.z; xs[n4 + 3][c] = xv.w;
    }
    #pragma unroll
    for (int i = 0; i < 4; ++i)
        reinterpret_cast<float4*>(&ws[0][0])[i * 256 + t] =
            reinterpret_cast<const float4*>(Wp)[i * 256 + t];
    __syncthreads();

    const int n  = t & 63;          // token within tile
    const int ob = (t >> 6) << 4;   // wave -> block of 16 output channels

    float acc[16];
    #pragma unroll
    for (int oo = 0; oo < 16; ++oo) acc[oo] = bp[ob + oo];
    for (int c4 = 0; c4 < 16; ++c4) {
        const float4 xv = *reinterpret_cast<const float4*>(&xs[n][c4 * 4]);
        #pragma unroll
        for (int oo = 0; oo < 16; ++oo) {
            const float4 wv = *reinterpret_cast<const float4*>(&ws[ob + oo][c4 * 4]);
            acc[oo] = fmaf(wv.x, xv.x, acc[oo]);
            acc[oo] = fmaf(wv.y, xv.y, acc[oo]);
            acc[oo] = fmaf(wv.z, xv.z, acc[oo]);
            acc[oo] = fmaf(wv.w, xv.w, acc[oo]);
        }
    }

    if (p < 2) {  // q (scaled by log2e), k: fp16, (N,C) layout
        f16* hp = (p == 0) ? qh : kh;
        const float qs = (p == 0) ? LOG2E : 1.0f;
        f16 hb[16];
        #pragma unroll
        for (int oo = 0; oo < 16; ++oo) hb[oo] = (f16)(acc[oo] * qs);
        const size_t base = ((size_t)(b * NT + n0 + n)) * NC + ob;
        *reinterpret_cast<f16x8*>(hp + base)     = *reinterpret_cast<const f16x8*>(&hb[0]);
        *reinterpret_cast<f16x8*>(hp + base + 8) = *reinterpret_cast<const f16x8*>(&hb[8]);
    } else {      // v: fp16, (C,N) layout
        const size_t vbase = (size_t)b * NC * NT + n0 + n;
        #pragma unroll
        for (int oo = 0; oo < 16; ++oo)
            vv[vbase + (size_t)(ob + oo) * NT] = (f16)acc[oo];
    }
}

// ---------------- kernel 2: flash attention (split-j, fp16, KVB=32) ----------------
// grid = splits * NB * 64 blocks of 256 threads (4 waves x 16 query rows).
// Block decode: XCD-chunked swizzle when (#groups % 8 == 0) so each XCD's L2
// holds only its own (split,batch) K/V slices.
__global__ __launch_bounds__(256, 8) void attn_fused(
    const f16* __restrict__ qh, const f16* __restrict__ kh,
    const f16* __restrict__ vv, float* __restrict__ out,
    f16* __restrict__ pacc, float* __restrict__ pm,
    float* __restrict__ pl, int nTiles, int direct)
{
    // XOR-swizzled LDS, no padding.
    __shared__ f16 khs[KVB * 64];      // K-tile [key][ch],   128B rows, swz (row&7)<<4
    __shared__ f16 vs_[64 * KVB];      // V-tile [ch][key],    64B rows, swz (row&3)<<4
    __shared__ f16 ps[4][16 * KVB];    // per-wave P [q][key], 64B rows, swz (row&3)<<4

    const int t    = threadIdx.x;
    const int lane = t & 63;
    const int wv   = t >> 6;
    const int c0   = lane & 15;   // A-row / B-col within subtile
    const int g    = lane >> 4;   // k-group 0..3

    // block decode (+ XCD swizzle)
    const int ngrp = (int)gridDim.x >> 6;   // # (split,batch) groups
    int grp, i0;
    if ((ngrp & 7) == 0) {
        const int gpx  = ngrp >> 3;
        const int slot = (int)blockIdx.x >> 3;
        grp = ((int)blockIdx.x & 7) * gpx + (slot >> 6);
        i0  = (slot & 63) << 6;
    } else {
        grp = (int)blockIdx.x >> 6;
        i0  = ((int)blockIdx.x & 63) << 6;
    }
    const int s = grp >> 2;       // split index
    const int b = grp & 3;        // batch

    // Q fragment (A-frag 16x16x32: lane row = lane&15, k = (lane>>4)*8+[0..7])
    f16x8 qf[2];
    {
        const size_t qoff = ((size_t)(b * NT + i0 + wv * 16 + c0)) * NC + g * 8;
        qf[0] = *reinterpret_cast<const f16x8*>(qh + qoff);
        qf[1] = *reinterpret_cast<const f16x8*>(qh + qoff + 32);
    }

    f32x4 acc[4] = {{0.f,0.f,0.f,0.f},{0.f,0.f,0.f,0.f},
                    {0.f,0.f,0.f,0.f},{0.f,0.f,0.f,0.f}};
    float m[4] = {-INFINITY, -INFINITY, -INFINITY, -INFINITY};
    float l[4] = {0.f, 0.f, 0.f, 0.f};

    // staging: K tile 32x64 = 256 chunks of 8 f16; V tile 64x32 = 256 chunks.
    const int krow = t >> 3, kc8 = (t & 7) << 3;   // K: row=key, 8-f16 chunk
    const int vrow = t >> 2, vc8 = (t & 3) << 3;   // V: row=ch,  8-f16 chunk
    const f16* kh_g = kh + (size_t)b * NT * NC;
    const f16* v_g  = vv + (size_t)b * NC * NT;

    char* const khsb = (char*)khs;
    char* const vsb  = (char*)vs_;
    char* const psb  = (char*)ps[wv];
    const int kwoff = krow * 128 + ((kc8 << 1) ^ ((krow & 7) << 4));
    const int vwoff = vrow * 64  + ((vc8 << 1) ^ ((vrow & 3) << 4));

    f16x8 stK, stV;
    auto stage_load = [&](int j0) {
        stK = *reinterpret_cast<const f16x8*>(kh_g + (size_t)(j0 + krow) * NC + kc8);
        stV = *reinterpret_cast<const f16x8*>(v_g + (size_t)vrow * NT + j0 + vc8);
    };

    const int t0 = s * nTiles;
    stage_load(t0 * KVB);

    for (int k = 0; k < nTiles; ++k) {
        __syncthreads();   // previous tile's LDS reads complete
        *reinterpret_cast<f16x8*>(khsb + kwoff) = stK;
        *reinterpret_cast<f16x8*>(vsb + vwoff)  = stV;
        __syncthreads();
        if (k + 1 < nTiles) stage_load((t0 + k + 1) * KVB);  // in flight under compute

        // ---- S' = (log2e*Q) K^T ----
        f32x4 sreg[2] = {{0.f,0.f,0.f,0.f},{0.f,0.f,0.f,0.f}};
        #pragma unroll
        for (int js = 0; js < 2; ++js) {
            #pragma unroll
            for (int kb = 0; kb < 2; ++kb) {
                const int row = js * 16 + c0;
                const int off = row * 128 + ((kb * 64 + g * 16) ^ ((c0 & 7) << 4));
                const f16x8 bh = *reinterpret_cast<const f16x8*>(khsb + off);
                sreg[js] = __builtin_amdgcn_mfma_f32_16x16x32_f16(qf[kb], bh, sreg[js], 0, 0, 0);
            }
        }

        // ---- online softmax, base-2 (D: col=lane&15=key, row=g*4+r=query) ----
        float mt[4], pr[2][4], rs[4], sc[4];
        #pragma unroll
        for (int r = 0; r < 4; ++r)
            mt[r] = fmaxf(sreg[0][r], sreg[1][r]);
        #pragma unroll
        for (int d = 1; d < 16; d <<= 1) {
            #pragma unroll
            for (int r = 0; r < 4; ++r)
                mt[r] = fmaxf(mt[r], __shfl_xor(mt[r], d));
        }
        #pragma unroll
        for (int r = 0; r < 4; ++r) {
            const float mn = fmaxf(m[r], mt[r]);
            sc[r] = fexp2(m[r] - mn);
            m[r] = mn;
            const float p0 = fexp2(sreg[0][r] - mn);
            const float p1 = fexp2(sreg[1][r] - mn);
            pr[0][r] = p0; pr[1][r] = p1;
            rs[r] = p0 + p1;
        }
        #pragma unroll
        for (int d = 1; d < 16; d <<= 1) {
            #pragma unroll
            for (int r = 0; r < 4; ++r)
                rs[r] += __shfl_xor(rs[r], d);
        }
        #pragma unroll
        for (int r = 0; r < 4; ++r) l[r] = l[r] * sc[r] + rs[r];
        #pragma unroll
        for (int cs = 0; cs < 4; ++cs)
            #pragma unroll
            for (int r = 0; r < 4; ++r)
                acc[cs][r] *= sc[r];

        // ---- P -> LDS (fp16), per-wave buffer (in-wave DS ordering) ----
        #pragma unroll
        for (int js = 0; js < 2; ++js)
            #pragma unroll
            for (int r = 0; r < 4; ++r) {
                const int row = g * 4 + r;
                const int off = row * 64 + ((((js * 16 + c0) << 1)) ^ ((row & 3) << 4));
                *reinterpret_cast<f16*>(psb + off) = (f16)pr[js][r];
            }

        // ---- O += P V ----
        {
            const f16x8 ap = *reinterpret_cast<const f16x8*>(
                psb + c0 * 64 + ((g * 16) ^ ((c0 & 3) << 4)));
            #pragma unroll
            for (int cs = 0; cs < 4; ++cs) {
                const int ch = cs * 16 + c0;
                const f16x8 bvv = *reinterpret_cast<const f16x8*>(
                    vsb + ch * 64 + ((g * 16) ^ ((c0 & 3) << 4)));
                acc[cs] = __builtin_amdgcn_mfma_f32_16x16x32_f16(ap, bvv, acc[cs], 0, 0, 0);
            }
        }
    }

    // ---- epilogue ----
    const int irow = i0 + wv * 16 + g * 4;
    float linv[4];
    #pragma unroll
    for (int r = 0; r < 4; ++r) linv[r] = 1.f / l[r];
    if (direct) {
        #pragma unroll
        for (int cs = 0; cs < 4; ++cs)
            #pragma unroll
            for (int r = 0; r < 4; ++r)
                out[(size_t)b * NC * NT + (size_t)(cs * 16 + c0) * NT + irow + r] =
                    acc[cs][r] * linv[r];
    } else {
        // store NORMALIZED partial o_s (fp16) + m (base-2), l (f32)
        const size_t pb = (size_t)(s * NB + b);
        #pragma unroll
        for (int cs = 0; cs < 4; ++cs)
            #pragma unroll
            for (int r = 0; r < 4; ++r)
                pacc[(pb * NC + cs * 16 + c0) * NT + irow + r] =
                    (f16)(acc[cs][r] * linv[r]);
        if (c0 == 0) {
            #pragma unroll
            for (int r = 0; r < 4; ++r) {
                pm[pb * NT + irow + r] = m[r];
                pl[pb * NT + irow + r] = l[r];
            }
        }
    }
}

// ---------------- kernel 3: merge split-j partials ----------------
// out = sum_s w_s l_s o_s / sum_s w_s l_s, w_s = 2^(m_s - M). Two passes over
// pm (tiny, L2-hot) to avoid runtime-indexed register arrays.
__global__ __launch_bounds__(256) void merge_partials(
    const f16* __restrict__ pacc, const float* __restrict__ pm,
    const float* __restrict__ pl, float* __restrict__ out, int splits)
{
    const int t = threadIdx.x;
    const int i = ((blockIdx.x & 15) << 8) + t;
    const int c = (blockIdx.x >> 4) & 63;
    const int b = blockIdx.x >> 10;

    float M = -INFINITY;
    for (int s = 0; s < splits; ++s)
        M = fmaxf(M, pm[(size_t)(s * NB + b) * NT + i]);
    float L = 0.f, A = 0.f;
    for (int s = 0; s < splits; ++s) {
        const size_t pb = (size_t)(s * NB + b);
        const float wl = fexp2(pm[pb * NT + i] - M) * pl[pb * NT + i];
        L += wl;
        A += wl * (float)pacc[(pb * NC + c) * NT + i];
    }
    out[((size_t)b * NC + c) * NT + i] = A / L;
}

extern "C" void kernel_launch(void* const* d_in, const int* in_sizes, int n_in,
                              void* d_out, int out_size, void* d_ws, size_t ws_size,
                              hipStream_t stream)
{
    const float* x  = (const float*)d_in[0];
    const float* Wq = (const float*)d_in[1];
    const float* bq = (const float*)d_in[2];
    const float* Wk = (const float*)d_in[3];
    const float* bk = (const float*)d_in[4];
    const float* Wv = (const float*)d_in[5];
    const float* bv = (const float*)d_in[6];
    float* out = (float*)d_out;

    // ws carve: qh,kh ((N,C) fp16) + v ((C,N) fp16) = 6 MB base,
    // then per-split: normalized o (fp16, S elems) + m,l (f32, NB*NT each).
    const size_t S = (size_t)NB * NT * NC;           // 1M elements
    const size_t base_bytes = 6 * S;                 // 3 fp16 arrays
    auto fits = [&](int sp) {
        return base_bytes + (size_t)sp * (2 * S + 2 * 4 * (size_t)NB * NT) <= ws_size;
    };
    const int splits = fits(8) ? 8 : fits(4) ? 4 : fits(2) ? 2 : fits(1) ? 1 : 0;

    f16* qh = (f16*)d_ws;
    f16* kh = qh + S;
    f16* vv = kh + S;

    qkv_proj<<<3 * NB * (NT / 64), 256, 0, stream>>>(x, Wq, bq, Wk, bk, Wv, bv,
                                                     qh, kh, vv);

    const int totTiles = NT / KVB;   // 128
    if (splits == 0) {
        attn_fused<<<NB * 64, 256, 0, stream>>>(
            qh, kh, vv, out, nullptr, nullptr, nullptr, totTiles, 1);
        return;
    }

    f16* pacc = vv + S;
    float* pm = (float*)(pacc + (size_t)splits * S);
    float* pl = pm + (size_t)splits * NB * NT;

    attn_fused<<<splits * NB * 64, 256, 0, stream>>>(
        qh, kh, vv, out, pacc, pm, pl, totTiles / splits, 0);
    merge_partials<<<NB * NC * (NT / 256), 256, 0, stream>>>(pacc, pm, pl, out, splits);
}

// Round 6
// 66.164 us; speedup vs baseline: 1.8081x; 1.8081x over previous
//
#include <hip/hip_runtime.h>
#include <hip/hip_bf16.h>

// Fused spatial self-attention, B=4 C=64 H=W=64 (N=4096), fp32 in/out.
// Round 6: KVB=64, splits=8, swapped-operand MFMA (S^T and O^T) so softmax
// state is per-lane scalar (query = lane&15); packed b64 P writes; XOR-swz
// LDS (24KB/block); launch_bounds(256,6); exp2 softmax; XCD-chunked grid.

using f16    = _Float16;
using f16x8  = __attribute__((ext_vector_type(8))) f16;
using f32x4  = __attribute__((ext_vector_type(4))) float;

static constexpr int NB = 4;     // batch
static constexpr int NC = 64;    // channels
static constexpr int NT = 4096;  // tokens (H*W)
static constexpr int KVB = 64;   // keys per j-tile
static constexpr float LOG2E = 1.44269504088896f;

__device__ __forceinline__ float fexp2(float x) { return __builtin_amdgcn_exp2f(x); }
__device__ __forceinline__ unsigned int pkf16(float a, float b) {
    const unsigned short ua = __builtin_bit_cast(unsigned short, (f16)a);
    const unsigned short ub = __builtin_bit_cast(unsigned short, (f16)b);
    return (unsigned int)ua | ((unsigned int)ub << 16);
}

// ---------------- kernel 1: QKV projection (exact fp32) ----------------
// grid = 3 * B * (N/64); blockIdx>>8 selects projection (q/k/v).
__global__ __launch_bounds__(256) void qkv_proj(
    const float* __restrict__ x,
    const float* __restrict__ Wq, const float* __restrict__ bq,
    const float* __restrict__ Wk, const float* __restrict__ bk,
    const float* __restrict__ Wv, const float* __restrict__ bv,
    f16* __restrict__ qh, f16* __restrict__ kh, f16* __restrict__ vv)
{
    __shared__ float xs[64][68];   // [n][c], transposed x tile (pad for b128)
    __shared__ float ws[64][64];   // projection weight [o][c]

    const int t  = threadIdx.x;
    const int p  = blockIdx.x >> 8;          // 0=q 1=k 2=v
    const int b  = (blockIdx.x >> 6) & 3;
    const int n0 = (blockIdx.x & 63) << 6;

    const float* Wp = (p == 0) ? Wq : (p == 1) ? Wk : Wv;
    const float* bp = (p == 0) ? bq : (p == 1) ? bk : bv;

    #pragma unroll
    for (int i = 0; i < 4; ++i) {
        const int idx = i * 256 + t;
        const int c = idx >> 4, n4 = (idx & 15) << 2;
        const float4 xv = *reinterpret_cast<const float4*>(
            x + ((size_t)(b * NC + c)) * NT + n0 + n4);
        xs[n4 + 0][c] = xv.x; xs[n4 + 1][c] = xv.y;
        xs[n4 + 2][c] = xv.z; xs[n4 + 3][c] = xv.w;
    }
    #pragma unroll
    for (int i = 0; i < 4; ++i)
        reinterpret_cast<float4*>(&ws[0][0])[i * 256 + t] =
            reinterpret_cast<const float4*>(Wp)[i * 256 + t];
    __syncthreads();

    const int n  = t & 63;          // token within tile
    const int ob = (t >> 6) << 4;   // wave -> block of 16 output channels

    float acc[16];
    #pragma unroll
    for (int oo = 0; oo < 16; ++oo) acc[oo] = bp[ob + oo];
    for (int c4 = 0; c4 < 16; ++c4) {
        const float4 xv = *reinterpret_cast<const float4*>(&xs[n][c4 * 4]);
        #pragma unroll
        for (int oo = 0; oo < 16; ++oo) {
            const float4 wv = *reinterpret_cast<const float4*>(&ws[ob + oo][c4 * 4]);
            acc[oo] = fmaf(wv.x, xv.x, acc[oo]);
            acc[oo] = fmaf(wv.y, xv.y, acc[oo]);
            acc[oo] = fmaf(wv.z, xv.z, acc[oo]);
            acc[oo] = fmaf(wv.w, xv.w, acc[oo]);
        }
    }

    if (p < 2) {  // q (x log2e), k: fp16, (N,C) layout
        f16* hp = (p == 0) ? qh : kh;
        const float qs = (p == 0) ? LOG2E : 1.0f;
        f16 hb[16];
        #pragma unroll
        for (int oo = 0; oo < 16; ++oo) hb[oo] = (f16)(acc[oo] * qs);
        const size_t base = ((size_t)(b * NT + n0 + n)) * NC + ob;
        *reinterpret_cast<f16x8*>(hp + base)     = *reinterpret_cast<const f16x8*>(&hb[0]);
        *reinterpret_cast<f16x8*>(hp + base + 8) = *reinterpret_cast<const f16x8*>(&hb[8]);
    } else {      // v: fp16, (C,N) layout
        const size_t vbase = (size_t)b * NC * NT + n0 + n;
        #pragma unroll
        for (int oo = 0; oo < 16; ++oo)
            vv[vbase + (size_t)(ob + oo) * NT] = (f16)acc[oo];
    }
}

// ---------------- kernel 2: flash attention (split-j, swapped MFMA) ----------------
// grid = splits * NB * 64 blocks, 256 thr (4 waves x 16 queries each).
__global__ __launch_bounds__(256, 6) void attn_fused(
    const f16* __restrict__ qh, const f16* __restrict__ kh,
    const f16* __restrict__ vv, float* __restrict__ out,
    f16* __restrict__ pacc, float* __restrict__ pm,
    float* __restrict__ pl, int nTiles, int direct)
{
    // XOR-swizzled LDS (byte ^= (row&7)<<4 within each 128B row), no padding.
    __shared__ f16 khs[KVB * 64];      // K-tile [key][ch]    8KB
    __shared__ f16 vs_[64 * KVB];      // V-tile [ch][key]    8KB
    __shared__ f16 ps[4][16 * KVB];    // per-wave P [query][key] 2KB each

    const int t    = threadIdx.x;
    const int lane = t & 63;
    const int wv   = t >> 6;
    const int c0   = lane & 15;   // query (and ch-sub for PV A-frag rows)
    const int g    = lane >> 4;   // k-group 0..3

    // block decode (+ XCD-chunked swizzle when #groups % 8 == 0)
    const int ngrp = (int)gridDim.x >> 6;
    int grp, i0;
    if ((ngrp & 7) == 0) {
        const int gpx  = ngrp >> 3;
        const int slot = (int)blockIdx.x >> 3;
        grp = ((int)blockIdx.x & 7) * gpx + (slot >> 6);
        i0  = (slot & 63) << 6;
    } else {
        grp = (int)blockIdx.x >> 6;
        i0  = ((int)blockIdx.x & 63) << 6;
    }
    const int s = grp >> 2;       // split index
    const int b = grp & 3;        // batch

    // Q fragment (B-frag for swapped QK^T): lane holds Q[query=c0][ch g*8..+7]
    f16x8 qf[2];
    {
        const size_t qoff = ((size_t)(b * NT + i0 + wv * 16 + c0)) * NC + g * 8;
        qf[0] = *reinterpret_cast<const f16x8*>(qh + qoff);
        qf[1] = *reinterpret_cast<const f16x8*>(qh + qoff + 32);
    }

    // acc = O^T fragments: acc[cs][r] = O[ch=cs*16+g*4+r][query=c0]
    f32x4 acc[4] = {{0.f,0.f,0.f,0.f},{0.f,0.f,0.f,0.f},
                    {0.f,0.f,0.f,0.f},{0.f,0.f,0.f,0.f}};
    float m = -INFINITY, l = 0.f;   // per-lane scalars (query c0)

    // staging: K 64x64 and V 64x64 f16 tiles, 512 chunks of 16B each ->
    // each thread 2 K-chunks + 2 V-chunks.
    const int row0 = t >> 3, c8 = (t & 7) << 3;   // chunk col (f16 idx)
    const f16* kh_g = kh + (size_t)b * NT * NC;
    const f16* v_g  = vv + (size_t)b * NC * NT;

    char* const khsb = (char*)khs;
    char* const vsb  = (char*)vs_;
    char* const psb  = (char*)ps[wv];
    // swizzled LDS write offsets (row*128 + (col_bytes ^ ((row&7)<<4)))
    const int kw0 = row0 * 128 + ((c8 << 1) ^ ((row0 & 7) << 4));
    const int kw1 = (row0 + 32) * 128 + ((c8 << 1) ^ (((row0 + 32) & 7) << 4));

    f16x8 stK0, stK1, stV0, stV1;
    auto stage_load = [&](int j0) {
        stK0 = *reinterpret_cast<const f16x8*>(kh_g + (size_t)(j0 + row0) * NC + c8);
        stK1 = *reinterpret_cast<const f16x8*>(kh_g + (size_t)(j0 + row0 + 32) * NC + c8);
        stV0 = *reinterpret_cast<const f16x8*>(v_g + (size_t)row0 * NT + j0 + c8);
        stV1 = *reinterpret_cast<const f16x8*>(v_g + (size_t)(row0 + 32) * NT + j0 + c8);
    };

    const int t0 = s * nTiles;
    stage_load(t0 * KVB);

    for (int k = 0; k < nTiles; ++k) {
        __syncthreads();   // previous tile's LDS reads complete
        *reinterpret_cast<f16x8*>(khsb + kw0) = stK0;
        *reinterpret_cast<f16x8*>(khsb + kw1) = stK1;
        *reinterpret_cast<f16x8*>(vsb + kw0)  = stV0;
        *reinterpret_cast<f16x8*>(vsb + kw1)  = stV1;
        __syncthreads();
        if (k + 1 < nTiles) stage_load((t0 + k + 1) * KVB);  // in flight

        // ---- S^T = K Q^T : sreg[js][r] = S[key=js*16+g*4+r][query=c0] ----
        f32x4 sreg[4] = {{0.f,0.f,0.f,0.f},{0.f,0.f,0.f,0.f},
                         {0.f,0.f,0.f,0.f},{0.f,0.f,0.f,0.f}};
        #pragma unroll
        for (int js = 0; js < 4; ++js) {
            const int row = js * 16 + c0;   // key row
            #pragma unroll
            for (int kb = 0; kb < 2; ++kb) {
                const int off = row * 128 + ((kb * 64 + g * 16) ^ ((c0 & 7) << 4));
                const f16x8 ak = *reinterpret_cast<const f16x8*>(khsb + off);
                sreg[js] = __builtin_amdgcn_mfma_f32_16x16x32_f16(ak, qf[kb], sreg[js], 0, 0, 0);
            }
        }

        // ---- online softmax, base-2; all state per-lane scalar ----
        float mt = sreg[0][0];
        #pragma unroll
        for (int js = 0; js < 4; ++js)
            #pragma unroll
            for (int r = 0; r < 4; ++r) mt = fmaxf(mt, sreg[js][r]);
        mt = fmaxf(mt, __shfl_xor(mt, 16));
        mt = fmaxf(mt, __shfl_xor(mt, 32));
        const float mn = fmaxf(m, mt);
        const float sc = fexp2(m - mn);
        m = mn;
        float pr[4][4], rs = 0.f;
        #pragma unroll
        for (int js = 0; js < 4; ++js)
            #pragma unroll
            for (int r = 0; r < 4; ++r) {
                pr[js][r] = fexp2(sreg[js][r] - mn);
                rs += pr[js][r];
            }
        rs += __shfl_xor(rs, 16);
        rs += __shfl_xor(rs, 32);
        l = l * sc + rs;
        #pragma unroll
        for (int cs = 0; cs < 4; ++cs)
            #pragma unroll
            for (int r = 0; r < 4; ++r) acc[cs][r] *= sc;

        // ---- P -> LDS as packed b64 (keys g*4..+3 contiguous per lane) ----
        #pragma unroll
        for (int js = 0; js < 4; ++js) {
            const unsigned int lo = pkf16(pr[js][0], pr[js][1]);
            const unsigned int hi = pkf16(pr[js][2], pr[js][3]);
            const int off = c0 * 128 + ((js * 32 + g * 8) ^ ((c0 & 7) << 4));
            *reinterpret_cast<uint2*>(psb + off) = make_uint2(lo, hi);
        }

        // ---- O^T += V^T P^T : acc[cs] over ch rows cs*16+g*4+r ----
        #pragma unroll
        for (int kb = 0; kb < 2; ++kb) {
            const int pof = c0 * 128 + ((kb * 64 + g * 16) ^ ((c0 & 7) << 4));
            const f16x8 bp8 = *reinterpret_cast<const f16x8*>(psb + pof);
            #pragma unroll
            for (int cs = 0; cs < 4; ++cs) {
                const int vrow = cs * 16 + c0;
                const int vof = vrow * 128 + ((kb * 64 + g * 16) ^ ((c0 & 7) << 4));
                const f16x8 av = *reinterpret_cast<const f16x8*>(vsb + vof);
                acc[cs] = __builtin_amdgcn_mfma_f32_16x16x32_f16(av, bp8, acc[cs], 0, 0, 0);
            }
        }
    }

    // ---- epilogue: O[ch][query]; query = i0 + wv*16 + c0 ----
    const int q = i0 + wv * 16 + c0;
    const float linv = 1.f / l;
    if (direct) {
        #pragma unroll
        for (int cs = 0; cs < 4; ++cs)
            #pragma unroll
            for (int r = 0; r < 4; ++r)
                out[(size_t)b * NC * NT + (size_t)(cs * 16 + g * 4 + r) * NT + q] =
                    acc[cs][r] * linv;
    } else {
        const size_t pb = (size_t)(s * NB + b);
        #pragma unroll
        for (int cs = 0; cs < 4; ++cs)
            #pragma unroll
            for (int r = 0; r < 4; ++r)
                pacc[(pb * NC + cs * 16 + g * 4 + r) * NT + q] =
                    (f16)(acc[cs][r] * linv);
        if (g == 0) {
            pm[pb * NT + q] = m;
            pl[pb * NT + q] = l;
        }
    }
}

// ---------------- kernel 3: merge split-j partials ----------------
__global__ __launch_bounds__(256) void merge_partials(
    const f16* __restrict__ pacc, const float* __restrict__ pm,
    const float* __restrict__ pl, float* __restrict__ out, int splits)
{
    const int t = threadIdx.x;
    const int i = ((blockIdx.x & 15) << 8) + t;
    const int c = (blockIdx.x >> 4) & 63;
    const int b = blockIdx.x >> 10;

    float M = -INFINITY;
    for (int s = 0; s < splits; ++s)
        M = fmaxf(M, pm[(size_t)(s * NB + b) * NT + i]);
    float L = 0.f, A = 0.f;
    for (int s = 0; s < splits; ++s) {
        const size_t pb = (size_t)(s * NB + b);
        const float wl = fexp2(pm[pb * NT + i] - M) * pl[pb * NT + i];
        L += wl;
        A += wl * (float)pacc[(pb * NC + c) * NT + i];
    }
    out[((size_t)b * NC + c) * NT + i] = A / L;
}

extern "C" void kernel_launch(void* const* d_in, const int* in_sizes, int n_in,
                              void* d_out, int out_size, void* d_ws, size_t ws_size,
                              hipStream_t stream)
{
    const float* x  = (const float*)d_in[0];
    const float* Wq = (const float*)d_in[1];
    const float* bq = (const float*)d_in[2];
    const float* Wk = (const float*)d_in[3];
    const float* bk = (const float*)d_in[4];
    const float* Wv = (const float*)d_in[5];
    const float* bv = (const float*)d_in[6];
    float* out = (float*)d_out;

    const size_t S = (size_t)NB * NT * NC;           // 1M elements
    const size_t base_bytes = 6 * S;                 // qh,kh,v fp16
    auto fits = [&](int sp) {
        return base_bytes + (size_t)sp * (2 * S + 2 * 4 * (size_t)NB * NT) <= ws_size;
    };
    const int splits = fits(8) ? 8 : fits(4) ? 4 : fits(2) ? 2 : fits(1) ? 1 : 0;

    f16* qh = (f16*)d_ws;
    f16* kh = qh + S;
    f16* vv = kh + S;

    qkv_proj<<<3 * NB * (NT / 64), 256, 0, stream>>>(x, Wq, bq, Wk, bk, Wv, bv,
                                                     qh, kh, vv);

    const int totTiles = NT / KVB;   // 64
    if (splits == 0) {
        attn_fused<<<NB * 64, 256, 0, stream>>>(
            qh, kh, vv, out, nullptr, nullptr, nullptr, totTiles, 1);
        return;
    }

    f16* pacc = vv + S;
    float* pm = (float*)(pacc + (size_t)splits * S);
    float* pl = pm + (size_t)splits * NB * NT;

    attn_fused<<<splits * NB * 64, 256, 0, stream>>>(
        qh, kh, vv, out, pacc, pm, pl, totTiles / splits, 0);
    merge_partials<<<NB * NC * (NT / 256), 256, 0, stream>>>(pacc, pm, pl, out, splits);
}